// Round 7
// baseline (576.890 us; speedup 1.0000x reference)
//
#include <hip/hip_runtime.h>
#include <hip/hip_bf16.h>

#define NROWS 16384
#define DIM   1024
#define NT    16                         // K-tiles (1024/64)
#define NTILE 64                         // 256-row tiles per dim
#define NBLK  (NTILE * (NTILE + 1) / 2)  // 2080 upper-tri blocks (2080 = 8*260)

typedef __bf16 bf16x8 __attribute__((ext_vector_type(8)));
typedef __bf16 bf16x4 __attribute__((ext_vector_type(4)));
typedef float  f32x4  __attribute__((ext_vector_type(4)));

// monotone float -> uint key (order-preserving), so atomicMax works on floats
__device__ __forceinline__ unsigned fkey(float f) {
    unsigned u = __float_as_uint(f);
    return (u & 0x80000000u) ? ~u : (u | 0x80000000u);
}
__device__ __forceinline__ float funkey(unsigned k) {
    unsigned u = (k & 0x80000000u) ? (k & 0x7fffffffu) : ~k;
    return __uint_as_float(u);
}

__global__ void normalize_rows(const float* __restrict__ x,
                               __hip_bfloat16* __restrict__ xn,
                               unsigned* __restrict__ rowmax) {
    const int row = blockIdx.x;
    const int t = threadIdx.x;                      // 256 threads, 1 float4 each
    const float4 v = ((const float4*)(x + (size_t)row * DIM))[t];
    float ss = v.x * v.x + v.y * v.y + v.z * v.z + v.w * v.w;
#pragma unroll
    for (int off = 32; off > 0; off >>= 1) ss += __shfl_xor(ss, off);
    __shared__ float wss[4];
    if ((t & 63) == 0) wss[t >> 6] = ss;
    __syncthreads();
    const float tot = wss[0] + wss[1] + wss[2] + wss[3];
    const float scale = 1.0f / fmaxf(sqrtf(tot), 1e-12f);
    bf16x4 o;
    o[0] = (__bf16)(v.x * scale);
    o[1] = (__bf16)(v.y * scale);
    o[2] = (__bf16)(v.z * scale);
    o[3] = (__bf16)(v.w * scale);
    *(bf16x4*)(xn + (size_t)row * DIM + t * 4) = o;
    if (t == 0) rowmax[row] = 0u;
}

// ---- simmax: A staged in LDS (XOR-swizzled, dbuf 2x32KB), B streamed from
// global (L2/L3-resident) directly into MFMA fragment registers. One raw
// barrier + vmcnt(0) per K-tile; NO intra-tile fences -- the compiler's
// counted lgkmcnt/vmcnt scheduling interleaves LDS reads, B loads, staging
// and MFMA (separate pipes overlap). ----

__device__ __forceinline__ void read_A_half(const char* bufb, int half, int wr,
                                            int l15, int hi, bf16x8 af[4][2]) {
#pragma unroll
    for (int m2 = 0; m2 < 4; ++m2)
#pragma unroll
        for (int kk = 0; kk < 2; ++kk) {
            const int rih = wr * 64 + m2 * 16 + l15;
            const int chn = (kk * 4 + hi) ^ (rih & 7);
            af[m2][kk] = *(const bf16x8*)(bufb + half * 16384 + rih * 128 + chn * 16);
        }
}

#define SB() __builtin_amdgcn_sched_barrier(0)

__global__ __launch_bounds__(512, 2)
void simmax_kernel(const __hip_bfloat16* __restrict__ xn,
                   unsigned* __restrict__ rowmax) {
    // T1: bijective XCD-chunked swizzle (2080 = 8 * 260)
    const int bid = blockIdx.x;
    int rem = (bid & 7) * (NBLK / 8) + (bid >> 3);
    int it = 0;
    while (rem >= NTILE - it) { rem -= NTILE - it; ++it; }
    const int jt = it + rem;
    const bool diag = (jt == it);
    const int rowBase = it * 256;
    const int colBase = jt * 256;

    __shared__ __align__(16) char ldsA[2][32768];   // A panel dbuf, 64 KiB

    const int t    = threadIdx.x;
    const int lane = t & 63;
    const int wid  = t >> 6;
    const int wr   = wid >> 2;      // 0..1 (M half-select within quadrant)
    const int wc   = wid & 3;       // 0..3 (N: wave cols = wc*64..wc*64+63)
    const int l15  = lane & 15;
    const int hi   = lane >> 4;

    // A staging: chunk c = j*512 + t (j=0..3), row = c>>3 (0..255), ch = c&7.
    // LDS dest LINEAR (c*16 B); SOURCE col pre-swizzled (ch ^ (row&7)) so the
    // swizzled ds_read finds its data (rule #21).
    const __hip_bfloat16* srcA[4];
#pragma unroll
    for (int j = 0; j < 4; ++j) {
        const int c   = j * 512 + t;
        const int row = c >> 3;
        const int ch  = c & 7;
        srcA[j] = xn + (size_t)(rowBase + row) * DIM + (ch ^ (row & 7)) * 8;
    }

    // B fragment base: lane reads 16B at xn[colBase + col][k + hi*8]
    const __hip_bfloat16* bbase = xn + (size_t)(colBase + wc * 64 + l15) * DIM + hi * 8;

    // prologue: stage A(tile 0) into buf 0
#pragma unroll
    for (int j = 0; j < 4; ++j) {
        __builtin_amdgcn_global_load_lds(
            (const __attribute__((address_space(1))) void*)srcA[j],
            (__attribute__((address_space(3))) void*)(&ldsA[0][0] + (j * 512 + wid * 64) * 16),
            16, 0, 0);
        srcA[j] += 64;
    }
    asm volatile("s_waitcnt vmcnt(0)" ::: "memory");
    __builtin_amdgcn_s_barrier();
    SB();

    f32x4 acc[8][4];
#pragma unroll
    for (int m = 0; m < 8; ++m)
#pragma unroll
        for (int n = 0; n < 4; ++n)
            acc[m][n] = (f32x4){0.f, 0.f, 0.f, 0.f};

#pragma unroll 2
    for (int tk = 0; tk < NT; ++tk) {
        char* curb = &ldsA[tk & 1][0];
        char* nxtb = &ldsA[(tk & 1) ^ 1][0];
        const bool pf = (tk + 1 < NT);

        // B fragments for this K-tile: 8 global b128 loads into regs.
        // b[qn][n2][kk] covers cols wc*64 + qn*32 + n2*16 + l15, k = kk*32+hi*8
        bf16x8 b[2][2][2];
#pragma unroll
        for (int qn = 0; qn < 2; ++qn)
#pragma unroll
            for (int n2 = 0; n2 < 2; ++n2)
#pragma unroll
                for (int kk = 0; kk < 2; ++kk)
                    b[qn][n2][kk] = *(const bf16x8*)(bbase
                        + (size_t)(qn * 32 + n2 * 16) * DIM + tk * 64 + kk * 32);

        // stage A(t+1) into the other buffer (dead since last barrier)
        if (pf) {
#pragma unroll
            for (int j = 0; j < 4; ++j) {
                __builtin_amdgcn_global_load_lds(
                    (const __attribute__((address_space(1))) void*)srcA[j],
                    (__attribute__((address_space(3))) void*)(nxtb + (j * 512 + wid * 64) * 16),
                    16, 0, 0);
                srcA[j] += 64;
            }
        }

        // A half 0 (rows wr*64 within rows 0..127) -> quadrants (0,*)
        {
            bf16x8 af[4][2];
            read_A_half(curb, 0, wr, l15, hi, af);
#pragma unroll
            for (int m2 = 0; m2 < 4; ++m2)
#pragma unroll
                for (int n2 = 0; n2 < 2; ++n2)
#pragma unroll
                    for (int kk = 0; kk < 2; ++kk) {
                        acc[m2][n2]     = __builtin_amdgcn_mfma_f32_16x16x32_bf16(
                            af[m2][kk], b[0][n2][kk], acc[m2][n2], 0, 0, 0);
                        acc[m2][n2 + 2] = __builtin_amdgcn_mfma_f32_16x16x32_bf16(
                            af[m2][kk], b[1][n2][kk], acc[m2][n2 + 2], 0, 0, 0);
                    }
        }
        // A half 1 (rows 128..255) -> quadrants (1,*)
        {
            bf16x8 af[4][2];
            read_A_half(curb, 1, wr, l15, hi, af);
#pragma unroll
            for (int m2 = 0; m2 < 4; ++m2)
#pragma unroll
                for (int n2 = 0; n2 < 2; ++n2)
#pragma unroll
                    for (int kk = 0; kk < 2; ++kk) {
                        acc[m2 + 4][n2]     = __builtin_amdgcn_mfma_f32_16x16x32_bf16(
                            af[m2][kk], b[0][n2][kk], acc[m2 + 4][n2], 0, 0, 0);
                        acc[m2 + 4][n2 + 2] = __builtin_amdgcn_mfma_f32_16x16x32_bf16(
                            af[m2][kk], b[1][n2][kk], acc[m2 + 4][n2 + 2], 0, 0, 0);
                    }
        }

        // one barrier per tile: stage loads (issued ~a tile ago) drained,
        // A(t+1) published; buffer parity flips.
        asm volatile("s_waitcnt vmcnt(0)" ::: "memory");
        SB();
        __builtin_amdgcn_s_barrier();
        SB();
    }

    // ---- epilogue: tile max reduction ----
    // acc[qm*4+m2][qn*2+n2]: row = qm*128 + wr*64 + m2*16 + g*4 + r,
    // col = wc*64 + qn*32 + n2*16 + cl   (C/D layout m89/m91)
    const int g  = lane >> 4;
    const int cl = lane & 15;

    if (diag) {
#pragma unroll
        for (int qm = 0; qm < 2; ++qm)
#pragma unroll
            for (int m2 = 0; m2 < 4; ++m2)
#pragma unroll
                for (int qn = 0; qn < 2; ++qn)
#pragma unroll
                    for (int n2 = 0; n2 < 2; ++n2)
#pragma unroll
                        for (int r = 0; r < 4; ++r) {
                            const int grow = qm * 128 + wr * 64 + m2 * 16 + g * 4 + r;
                            const int gcol = wc * 64 + qn * 32 + n2 * 16 + cl;
                            if (grow == gcol) acc[qm * 4 + m2][qn * 2 + n2][r] = -3.0f;
                        }
    }

    // row-direction max (this wave's 64 cols), reduce over cl lanes
#pragma unroll
    for (int qm = 0; qm < 2; ++qm)
#pragma unroll
        for (int m2 = 0; m2 < 4; ++m2)
#pragma unroll
            for (int r = 0; r < 4; ++r) {
                const int am = qm * 4 + m2;
                float v = fmaxf(fmaxf(acc[am][0][r], acc[am][1][r]),
                                fmaxf(acc[am][2][r], acc[am][3][r]));
                v = fmaxf(v, __shfl_xor(v, 1));
                v = fmaxf(v, __shfl_xor(v, 2));
                v = fmaxf(v, __shfl_xor(v, 4));
                v = fmaxf(v, __shfl_xor(v, 8));
                if (cl == 0) {
                    const int grow = rowBase + qm * 128 + wr * 64 + m2 * 16 + g * 4 + r;
                    atomicMax(rowmax + grow, fkey(v));
                }
            }

    // col-direction max (transpose contribution), skip on diagonal tiles
    if (!diag) {
#pragma unroll
        for (int qn = 0; qn < 2; ++qn)
#pragma unroll
            for (int n2 = 0; n2 < 2; ++n2) {
                const int an = qn * 2 + n2;
                float v = -3.0f;
#pragma unroll
                for (int m = 0; m < 8; ++m)
#pragma unroll
                    for (int r = 0; r < 4; ++r)
                        v = fmaxf(v, acc[m][an][r]);
                v = fmaxf(v, __shfl_xor(v, 16));
                v = fmaxf(v, __shfl_xor(v, 32));
                if (g == 0) {
                    const int gcol = colBase + wc * 64 + qn * 32 + n2 * 16 + cl;
                    atomicMax(rowmax + gcol, fkey(v));
                }
            }
    }
}

__global__ void finalize_kernel(const unsigned* __restrict__ rowmax,
                                float* __restrict__ out) {
    const int t = threadIdx.x;
    float s = 0.f;
    for (int r = t; r < NROWS; r += 256) {
        const float m = fminf(funkey(rowmax[r]), 1.0f);   // NaN guard
        s += logf(2.0f - 2.0f * m + 1e-8f);
    }
#pragma unroll
    for (int off = 32; off > 0; off >>= 1) s += __shfl_xor(s, off);
    __shared__ float ws[4];
    if ((t & 63) == 0) ws[t >> 6] = s;
    __syncthreads();
    if (t == 0) out[0] = -0.5f * (ws[0] + ws[1] + ws[2] + ws[3]) / (float)NROWS;
}

extern "C" void kernel_launch(void* const* d_in, const int* in_sizes, int n_in,
                              void* d_out, int out_size, void* d_ws, size_t ws_size,
                              hipStream_t stream) {
    const float* x = (const float*)d_in[0];
    __hip_bfloat16* xn = (__hip_bfloat16*)d_ws;
    unsigned* rowmax = (unsigned*)((char*)d_ws + (size_t)NROWS * DIM * sizeof(__hip_bfloat16));
    float* out = (float*)d_out;

    normalize_rows<<<NROWS, 256, 0, stream>>>(x, xn, rowmax);
    simmax_kernel<<<NBLK, 512, 0, stream>>>(xn, rowmax);
    finalize_kernel<<<1, 256, 0, stream>>>(rowmax, out);
}

// Round 8
// 406.755 us; speedup vs baseline: 1.4183x; 1.4183x over previous
//
#include <hip/hip_runtime.h>
#include <hip/hip_bf16.h>

#define NROWS 16384
#define DIM   1024
#define NT    16                         // K-tiles (1024/64)
#define NTILE 64                         // 256-row tiles per dim
#define NBLK  (NTILE * (NTILE + 1) / 2)  // 2080 upper-tri blocks (2080 = 8*260)

typedef __bf16 bf16x8 __attribute__((ext_vector_type(8)));
typedef __bf16 bf16x4 __attribute__((ext_vector_type(4)));
typedef float  f32x4  __attribute__((ext_vector_type(4)));

// monotone float -> uint key (order-preserving), so atomicMax works on floats
__device__ __forceinline__ unsigned fkey(float f) {
    unsigned u = __float_as_uint(f);
    return (u & 0x80000000u) ? ~u : (u | 0x80000000u);
}
__device__ __forceinline__ float funkey(unsigned k) {
    unsigned u = (k & 0x80000000u) ? (k & 0x7fffffffu) : ~k;
    return __uint_as_float(u);
}

__global__ void normalize_rows(const float* __restrict__ x,
                               __hip_bfloat16* __restrict__ xn,
                               unsigned* __restrict__ rowmax) {
    const int row = blockIdx.x;
    const int t = threadIdx.x;                      // 256 threads, 1 float4 each
    const float4 v = ((const float4*)(x + (size_t)row * DIM))[t];
    float ss = v.x * v.x + v.y * v.y + v.z * v.z + v.w * v.w;
#pragma unroll
    for (int off = 32; off > 0; off >>= 1) ss += __shfl_xor(ss, off);
    __shared__ float wss[4];
    if ((t & 63) == 0) wss[t >> 6] = ss;
    __syncthreads();
    const float tot = wss[0] + wss[1] + wss[2] + wss[3];
    const float scale = 1.0f / fmaxf(sqrtf(tot), 1e-12f);
    bf16x4 o;
    o[0] = (__bf16)(v.x * scale);
    o[1] = (__bf16)(v.y * scale);
    o[2] = (__bf16)(v.z * scale);
    o[3] = (__bf16)(v.w * scale);
    *(bf16x4*)(xn + (size_t)row * DIM + t * 4) = o;
    if (t == 0) rowmax[row] = 0u;
}

// ---- simmax: R4 memory plan, compiler-scheduled tile body ----
// A+B staged via global_load_lds (XOR-swizzled source, linear LDS dest,
// 128KiB dbuf). Per K-tile: 8 stage loads issued at tile TOP (so the
// end-of-tile vmcnt(0) drains loads ~a full tile old), 24 unique
// ds_read_b128 + 64 MFMA free-scheduled by the compiler (counted lgkmcnt),
// ONE raw s_barrier + vmcnt(0) per tile, exactly two sched fences
// (dbuf-correctness pin + stage-early pin). No setprio, no other fences.

__device__ __forceinline__ void stage_half(const __hip_bfloat16* src, char* dstbase, int wid) {
#pragma unroll
    for (int j = 0; j < 2; ++j) {
        __builtin_amdgcn_global_load_lds(
            (const __attribute__((address_space(1))) void*)(src + (size_t)j * 64 * DIM),
            (__attribute__((address_space(3))) void*)(dstbase + (j * 512 + wid * 64) * 16),
            16, 0, 0);
    }
}

template<int QM>
__device__ __forceinline__ void read_A(const char* bufb, int wr, int l15, int hi,
                                       bf16x8 af[4][2]) {
#pragma unroll
    for (int m2 = 0; m2 < 4; ++m2)
#pragma unroll
        for (int kk = 0; kk < 2; ++kk) {
            const int rih = wr * 64 + m2 * 16 + l15;
            const int chn = (kk * 4 + hi) ^ (rih & 7);
            af[m2][kk] = *(const bf16x8*)(bufb + QM * 16384 + rih * 128 + chn * 16);
        }
}

template<int QN>
__device__ __forceinline__ void read_B(const char* bufb, int wc, int l15, int hi,
                                       bf16x8 bfr[2][2]) {
#pragma unroll
    for (int n2 = 0; n2 < 2; ++n2)
#pragma unroll
        for (int kk = 0; kk < 2; ++kk) {
            const int rih = wc * 32 + n2 * 16 + l15;
            const int chn = (kk * 4 + hi) ^ (rih & 7);
            bfr[n2][kk] = *(const bf16x8*)(bufb + 32768 + QN * 16384 + rih * 128 + chn * 16);
        }
}

template<int QM, int QN>
__device__ __forceinline__ void mfma16(f32x4 acc[8][4], bf16x8 af[4][2], bf16x8 bfr[2][2]) {
#pragma unroll
    for (int m2 = 0; m2 < 4; ++m2)
#pragma unroll
        for (int n2 = 0; n2 < 2; ++n2)
#pragma unroll
            for (int kk = 0; kk < 2; ++kk)
                acc[QM * 4 + m2][QN * 2 + n2] = __builtin_amdgcn_mfma_f32_16x16x32_bf16(
                    af[m2][kk], bfr[n2][kk], acc[QM * 4 + m2][QN * 2 + n2], 0, 0, 0);
}

#define SB() __builtin_amdgcn_sched_barrier(0)

__global__ __launch_bounds__(512, 2)
void simmax_kernel(const __hip_bfloat16* __restrict__ xn,
                   unsigned* __restrict__ rowmax) {
    // T1: bijective XCD-chunked swizzle (2080 = 8 * 260)
    const int bid = blockIdx.x;
    int rem = (bid & 7) * (NBLK / 8) + (bid >> 3);
    int it = 0;
    while (rem >= NTILE - it) { rem -= NTILE - it; ++it; }
    const int jt = it + rem;
    const bool diag = (jt == it);
    const int rowBase = it * 256;
    const int colBase = jt * 256;

    __shared__ __align__(16) char ldsraw[2][4][16384];  // [buf][A0,A1,B0,B1] 128 KiB

    const int t    = threadIdx.x;
    const int lane = t & 63;
    const int wid  = t >> 6;
    const int wr   = wid >> 2;      // 0..1 (M)
    const int wc   = wid & 3;       // 0..3 (N)
    const int l15  = lane & 15;
    const int hi   = lane >> 4;

    // staging source: row = halfbase + j*64 + (t>>3), col pre-swizzled so the
    // swizzled ds_read finds its data; LDS dest stays linear (rule #21)
    const int rowoff = t >> 3;
    const int scol   = ((t & 7) ^ ((t >> 3) & 7)) * 8;
    const __hip_bfloat16* srcp[4];
    srcp[0] = xn + (size_t)(rowBase +       rowoff) * DIM + scol;   // A0
    srcp[1] = xn + (size_t)(rowBase + 128 + rowoff) * DIM + scol;   // A1
    srcp[2] = xn + (size_t)(colBase +       rowoff) * DIM + scol;   // B0
    srcp[3] = xn + (size_t)(colBase + 128 + rowoff) * DIM + scol;   // B1

    // prologue: stage tile 0 into buf 0, drain once
#pragma unroll
    for (int h = 0; h < 4; ++h) {
        stage_half(srcp[h], &ldsraw[0][h][0], wid);
        srcp[h] += 64;
    }
    asm volatile("s_waitcnt vmcnt(0)" ::: "memory");
    __builtin_amdgcn_s_barrier();
    SB();

    f32x4 acc[8][4];
#pragma unroll
    for (int m = 0; m < 8; ++m)
#pragma unroll
        for (int n = 0; n < 4; ++n)
            acc[m][n] = (f32x4){0.f, 0.f, 0.f, 0.f};

    for (int tk = 0; tk < NT; ++tk) {
        char* curb = &ldsraw[tk & 1][0][0];
        char* nxtb = &ldsraw[(tk & 1) ^ 1][0][0];
        const bool pf = (tk + 1 < NT);

        // all 8 stage loads for tile t+1 at tile TOP (max age before drain);
        // writes target the buffer tile t never reads (dbuf-safe)
        if (pf) {
#pragma unroll
            for (int h = 0; h < 4; ++h) {
                stage_half(srcp[h], nxtb + h * 16384, wid);
                srcp[h] += 64;
            }
        }
        SB();   // pin stages at tile top; reads/MFMAs below schedule freely

        bf16x8 af[4][2], b0[2][2], b1[2][2];
        read_A<0>(curb, wr, l15, hi, af);
        read_B<0>(curb, wc, l15, hi, b0);
        mfma16<0, 0>(acc, af, b0);
        read_B<1>(curb, wc, l15, hi, b1);
        mfma16<0, 1>(acc, af, b1);
        read_A<1>(curb, wr, l15, hi, af);   // af reuse: half-0 frags dead
        mfma16<1, 1>(acc, af, b1);
        mfma16<1, 0>(acc, af, b0);

        // one barrier per tile: own reads complete (compiler lgkm), stages
        // for t+1 drained (issued ~a full tile ago), buffer parity flips
        asm volatile("s_waitcnt vmcnt(0)" ::: "memory");
        __builtin_amdgcn_s_barrier();
        SB();   // pin next tile's ds_reads below the barrier (dbuf safety)
    }

    // ---- epilogue: tile max reduction ----
    // acc[qm*4+m2][qn*2+n2]; row = qm*128 + wr*64 + m2*16 + g*4 + r,
    // col = qn*128 + wc*32 + n2*16 + cl  (C/D layout m89/m91)
    const int g  = lane >> 4;
    const int cl = lane & 15;

    if (diag) {
#pragma unroll
        for (int qm = 0; qm < 2; ++qm)
#pragma unroll
            for (int m2 = 0; m2 < 4; ++m2)
#pragma unroll
                for (int qn = 0; qn < 2; ++qn)
#pragma unroll
                    for (int n2 = 0; n2 < 2; ++n2)
#pragma unroll
                        for (int r = 0; r < 4; ++r) {
                            const int grow = qm * 128 + wr * 64 + m2 * 16 + g * 4 + r;
                            const int gcol = qn * 128 + wc * 32 + n2 * 16 + cl;
                            if (grow == gcol) acc[qm * 4 + m2][qn * 2 + n2][r] = -3.0f;
                        }
    }

    // row-direction max
#pragma unroll
    for (int qm = 0; qm < 2; ++qm)
#pragma unroll
        for (int m2 = 0; m2 < 4; ++m2)
#pragma unroll
            for (int r = 0; r < 4; ++r) {
                const int am = qm * 4 + m2;
                float v = fmaxf(fmaxf(acc[am][0][r], acc[am][1][r]),
                                fmaxf(acc[am][2][r], acc[am][3][r]));
                v = fmaxf(v, __shfl_xor(v, 1));
                v = fmaxf(v, __shfl_xor(v, 2));
                v = fmaxf(v, __shfl_xor(v, 4));
                v = fmaxf(v, __shfl_xor(v, 8));
                if (cl == 0) {
                    const int grow = rowBase + qm * 128 + wr * 64 + m2 * 16 + g * 4 + r;
                    atomicMax(rowmax + grow, fkey(v));
                }
            }

    // col-direction max (transpose contribution), skip on diagonal tiles
    if (!diag) {
#pragma unroll
        for (int qn = 0; qn < 2; ++qn)
#pragma unroll
            for (int n2 = 0; n2 < 2; ++n2) {
                const int an = qn * 2 + n2;
                float v = -3.0f;
#pragma unroll
                for (int m = 0; m < 8; ++m)
#pragma unroll
                    for (int r = 0; r < 4; ++r)
                        v = fmaxf(v, acc[m][an][r]);
                v = fmaxf(v, __shfl_xor(v, 16));
                v = fmaxf(v, __shfl_xor(v, 32));
                if (g == 0) {
                    const int gcol = colBase + qn * 128 + wc * 32 + n2 * 16 + cl;
                    atomicMax(rowmax + gcol, fkey(v));
                }
            }
    }
}

__global__ void finalize_kernel(const unsigned* __restrict__ rowmax,
                                float* __restrict__ out) {
    const int t = threadIdx.x;
    float s = 0.f;
    for (int r = t; r < NROWS; r += 256) {
        const float m = fminf(funkey(rowmax[r]), 1.0f);   // NaN guard
        s += logf(2.0f - 2.0f * m + 1e-8f);
    }
#pragma unroll
    for (int off = 32; off > 0; off >>= 1) s += __shfl_xor(s, off);
    __shared__ float ws[4];
    if ((t & 63) == 0) ws[t >> 6] = s;
    __syncthreads();
    if (t == 0) out[0] = -0.5f * (ws[0] + ws[1] + ws[2] + ws[3]) / (float)NROWS;
}

extern "C" void kernel_launch(void* const* d_in, const int* in_sizes, int n_in,
                              void* d_out, int out_size, void* d_ws, size_t ws_size,
                              hipStream_t stream) {
    const float* x = (const float*)d_in[0];
    __hip_bfloat16* xn = (__hip_bfloat16*)d_ws;
    unsigned* rowmax = (unsigned*)((char*)d_ws + (size_t)NROWS * DIM * sizeof(__hip_bfloat16));
    float* out = (float*)d_out;

    normalize_rows<<<NROWS, 256, 0, stream>>>(x, xn, rowmax);
    simmax_kernel<<<NBLK, 512, 0, stream>>>(xn, rowmax);
    finalize_kernel<<<1, 256, 0, stream>>>(rowmax, out);
}